// Round 13
// baseline (132.833 us; speedup 1.0000x reference)
//
#include <hip/hip_runtime.h>

// Problem: BS=64, N=1024, XC=1024, K=256, YS=768
//   y_k[b,k]   = sum_s y[b,s] * W_y[k,s]
//   z[b,n,k]   = tanh( sum_c x[b,n,c]*W_ch[k,c] + b_ch[k] + y_k[b,k] )
//   out[b*n,k] = softmax_k(z)
// bf16 MFMA GEMM (f32 acc) fused with tanh+softmax epilogue.
// R13: R9 (best, 111.4us) + persistent 2-tile blocks (grid 512, one
//      generation) with cross-tile overlap: tile-1's A(t0..t0+2)/B(t0)
//      issued in tile-0's dead tail slots so the whole epilogue-0 runs
//      with tile-1 loads in flight; epilogue barriers lgkm-only (no
//      vmcnt(0) drain); staging cvt = 2-op biased-round pack.

#define XC    1024
#define KOUT  256
#define NT    16        // K-steps: 1024 / 64
#define LDSZ  16384     // A double-buffer: 2 x 8KB (epilogue scratch aliases)

typedef float        f32x4_t  __attribute__((ext_vector_type(4)));
typedef unsigned int u32x4_t  __attribute__((ext_vector_type(4)));
typedef unsigned int u32x2_t  __attribute__((ext_vector_type(2)));
typedef __bf16       bf16x8_t __attribute__((ext_vector_type(8)));

__device__ __forceinline__ unsigned short f2bf(float f) {
  unsigned int u = __float_as_uint(f);
  u += 0x7fffu + ((u >> 16) & 1u);        // RNE (prep kernel only)
  return (unsigned short)(u >> 16);
}

// biased round-half-away pack: 2 floats -> 2 bf16 (0.5-ulp, R12-verified)
__device__ __forceinline__ unsigned int pack2bf(float a, float b) {
  unsigned int ua = __float_as_uint(a) + 0x8000u;
  unsigned int ub = __float_as_uint(b) + 0x8000u;
  return (ua >> 16) | (ub & 0xffff0000u);
}

__device__ __forceinline__ float fast_tanh(float v) {
  float e = __expf(2.0f * v);
  return 1.0f - 2.0f / (e + 1.0f);
}

// lgkm-only barrier: ds ops visible, global loads/stores STAY IN FLIGHT.
#define LGKM_BARRIER() do {                                  \
    asm volatile("s_waitcnt lgkmcnt(0)" ::: "memory");       \
    __builtin_amdgcn_s_barrier();                            \
    __builtin_amdgcn_sched_barrier(0);                       \
  } while (0)

// ---- prep kernel: blocks 0..255 convert W_ch -> fragment-ordered bf16;
//      blocks 256..319 compute bias[b][k] = y[b]·W_y[k] + b_ch[k] (f32).
__global__ void prep_kernel(const float* __restrict__ Wch,
                            const float* __restrict__ y,
                            const float* __restrict__ Wy,
                            const float* __restrict__ bch,
                            unsigned short* __restrict__ wbf,
                            float* __restrict__ biasws) {
  if (blockIdx.x < 256) {
    const int k = blockIdx.x;            // 0..255
    const int u = threadIdx.x;           // 0..255 ; c0 = 4u
    f32x4_t v = ((const f32x4_t*)(Wch + k * XC))[u];
    const int c0   = u << 2;
    const int t    = c0 >> 6;            // K-step tile
    const int ch   = (c0 & 63) >> 3;     // 16B chunk within tile
    const int kk   = ch >> 2;
    const int lg   = ch & 3;
    const int half = (c0 >> 2) & 1;      // which 8B of the 16B chunk
    const int wv   = k >> 6;
    const int ni   = (k >> 4) & 3;
    const int lr   = k & 15;
    const int lane = (lg << 4) | lr;
    unsigned int lo = (unsigned int)f2bf(v.x) | ((unsigned int)f2bf(v.y) << 16);
    unsigned int hi = (unsigned int)f2bf(v.z) | ((unsigned int)f2bf(v.w) << 16);
    char* p = (char*)wbf +
              ((size_t)((((t << 2) + wv) * 2 + kk) * 4 + ni) << 10) +
              (lane << 4) + (half << 3);
    *(u32x2_t*)p = (u32x2_t){lo, hi};
  } else {
    __shared__ __align__(16) float ys[768];
    const int b = blockIdx.x - 256;      // 0..63
    const int k = threadIdx.x;           // 0..255
    for (int i = k; i < 768; i += 256) ys[i] = y[b * 768 + i];
    __syncthreads();
    const f32x4_t* w4 = (const f32x4_t*)(Wy + k * 768);
    const f32x4_t* y4 = (const f32x4_t*)ys;
    float s = 0.f;
#pragma unroll 8
    for (int i = 0; i < 192; ++i) {
      f32x4_t w = w4[i], a = y4[i];
      s = fmaf(w.x, a.x, s); s = fmaf(w.y, a.y, s);
      s = fmaf(w.z, a.z, s); s = fmaf(w.w, a.w, s);
    }
    biasws[b * 256 + k] = s + bch[k];
  }
}

// ---- main fused kernel: persistent block does TWO 64-row tiles.
__global__ __launch_bounds__(256, 2) void fused_kernel(
    const float* __restrict__ x, const unsigned short* __restrict__ wbf,
    const float* __restrict__ bias, float* __restrict__ out) {
  __shared__ __align__(16) unsigned char smem[LDSZ];
  const int tid = threadIdx.x;
  const int l   = tid & 63;
  const int wv  = tid >> 6;            // wave 0..3 -> output cols [64w,64w+64)
  const int lr  = l & 15;
  const int lg  = l >> 4;
  const int m0a = blockIdx.x << 6;          // tile-0 first row
  const int m0b = (blockIdx.x + 512) << 6;  // tile-1 first row
  const int rr  = tid >> 4;            // A-stage: row-within-16-group
  const int c4  = tid & 15;            // A-stage: float4 column chunk
  const int t0  = blockIdx.x & 15;     // per-block K-phase rotation (R9)

  f32x4_t acc[4][4];
  const float* xb0 = x + (size_t)m0a * XC + (size_t)rr * XC + (c4 << 2);
  const float* xb1 = x + (size_t)m0b * XC + (size_t)rr * XC + (c4 << 2);
  const char* wsrc = (const char*)wbf + (wv << 13) + (l << 4);
  f32x4_t av0[4], av1[4], av2[4];      // 3-deep A prefetch, NAMED slots
  bf16x8_t bfrA[8], bfrB[8];           // [kk*4+nj], double-buffered

#define ZERO_ACC() do {                                                      \
    _Pragma("unroll")                                                        \
    for (int i = 0; i < 4; ++i)                                              \
      _Pragma("unroll")                                                      \
      for (int j = 0; j < 4; ++j) acc[i][j] = (f32x4_t){0.f, 0.f, 0.f, 0.f}; \
  } while (0)

#define LOADA(dst, base, tt) do {                                            \
    _Pragma("unroll")                                                        \
    for (int j = 0; j < 4; ++j)                                              \
      dst[j] = *(const f32x4_t*)((base) + (size_t)(j << 4) * XC + ((tt) << 6));\
  } while (0)

#define LOADB(dst, tt) do {                                                  \
    const char* g = wsrc + (size_t)(tt) * 32768;                             \
    _Pragma("unroll")                                                        \
    for (int f = 0; f < 8; ++f)                                              \
      dst[f] = __builtin_bit_cast(bf16x8_t, *(const u32x4_t*)(g + (f << 10)));\
  } while (0)

#define WRITEA(src, buf) do {                                                \
    _Pragma("unroll")                                                        \
    for (int j = 0; j < 4; ++j) {                                            \
      const int row = (j << 4) + rr;                                         \
      unsigned int lo = pack2bf(src[j].x, src[j].y);                         \
      unsigned int hi = pack2bf(src[j].z, src[j].w);                         \
      char* p = (char*)smem + ((buf) << 13) + row * 128 +                    \
                (((c4 >> 1) ^ (row & 7)) << 4) + ((c4 & 1) << 3);            \
      *(u32x2_t*)p = (u32x2_t){lo, hi};                                      \
    }                                                                        \
  } while (0)

#define COMPUTE(buf, bsrc) do {                                              \
    const u32x4_t* aB = (const u32x4_t*)(smem + ((buf) << 13));              \
    _Pragma("unroll")                                                        \
    for (int kk = 0; kk < 2; ++kk) {                                         \
      const int cs = ((kk << 2) | lg) ^ (lr & 7);                            \
      bf16x8_t afr[4];                                                       \
      _Pragma("unroll")                                                      \
      for (int mi = 0; mi < 4; ++mi)                                         \
        afr[mi] = __builtin_bit_cast(bf16x8_t, aB[(((mi << 4) + lr) << 3) + cs]);\
      _Pragma("unroll")                                                      \
      for (int mi = 0; mi < 4; ++mi)                                         \
        _Pragma("unroll")                                                    \
        for (int nj = 0; nj < 4; ++nj)                                       \
          acc[mi][nj] = __builtin_amdgcn_mfma_f32_16x16x32_bf16(             \
              afr[mi], bsrc[(kk << 2) | nj], acc[mi][nj], 0, 0, 0);          \
    }                                                                        \
  } while (0)

  // STEP: literal slots; K-tile index rotated by t0.
#define STEP(s, bC, bN, aW, aL, XB) do {                                     \
    LOADB(bN, (((s) + 1 + t0) & 15));                                        \
    LOADA(aL, XB, (((s) + 3 + t0) & 15));                                    \
    COMPUTE((s) & 1, bC);                                                    \
    WRITEA(aW, ((s) + 1) & 1);                                               \
    LGKM_BARRIER();                                                          \
  } while (0)

  // ---- EPILOGUE macro: tanh + row-softmax + store; lgkm-only barriers.
#define EPILOGUE(M0V, BIDXV) do {                                            \
    float* wred    = (float*)smem;                                           \
    float* rowstat = (float*)(smem + 1024);                                  \
    float brow[4];                                                           \
    _Pragma("unroll")                                                        \
    for (int ni = 0; ni < 4; ++ni)                                           \
      brow[ni] = bias[((BIDXV) << 8) + (wv << 6) + (ni << 4) + lr];          \
    _Pragma("unroll")                                                        \
    for (int mi = 0; mi < 4; ++mi)                                           \
      _Pragma("unroll")                                                      \
      for (int ni = 0; ni < 4; ++ni)                                         \
        _Pragma("unroll")                                                    \
        for (int r = 0; r < 4; ++r)                                          \
          acc[mi][ni][r] = fast_tanh(acc[mi][ni][r] + brow[ni]);             \
    _Pragma("unroll")                                                        \
    for (int mi = 0; mi < 4; ++mi)                                           \
      _Pragma("unroll")                                                      \
      for (int r = 0; r < 4; ++r) {                                          \
        float m = fmaxf(fmaxf(acc[mi][0][r], acc[mi][1][r]),                 \
                        fmaxf(acc[mi][2][r], acc[mi][3][r]));                \
        m = fmaxf(m, __shfl_xor(m, 1));                                      \
        m = fmaxf(m, __shfl_xor(m, 2));                                      \
        m = fmaxf(m, __shfl_xor(m, 4));                                      \
        m = fmaxf(m, __shfl_xor(m, 8));                                      \
        if (lr == 0) wred[(wv << 6) + (mi << 4) + (lg << 2) + r] = m;        \
      }                                                                      \
    LGKM_BARRIER();                                                          \
    if (tid < 64)                                                            \
      rowstat[tid] = fmaxf(fmaxf(wred[tid], wred[64 + tid]),                 \
                           fmaxf(wred[128 + tid], wred[192 + tid]));         \
    LGKM_BARRIER();                                                          \
    _Pragma("unroll")                                                        \
    for (int mi = 0; mi < 4; ++mi)                                           \
      _Pragma("unroll")                                                      \
      for (int r = 0; r < 4; ++r) {                                          \
        const int row = (mi << 4) + (lg << 2) + r;                           \
        const float m = rowstat[row];                                        \
        float s = 0.f;                                                       \
        _Pragma("unroll")                                                    \
        for (int ni = 0; ni < 4; ++ni) {                                     \
          float e = __expf(acc[mi][ni][r] - m);                              \
          acc[mi][ni][r] = e;                                                \
          s += e;                                                            \
        }                                                                    \
        s += __shfl_xor(s, 1);                                               \
        s += __shfl_xor(s, 2);                                               \
        s += __shfl_xor(s, 4);                                               \
        s += __shfl_xor(s, 8);                                               \
        if (lr == 0) wred[(wv << 6) + row] = s;                              \
      }                                                                      \
    LGKM_BARRIER();                                                          \
    if (tid < 64)                                                            \
      rowstat[tid] = 1.0f / (wred[tid] + wred[64 + tid] +                    \
                             wred[128 + tid] + wred[192 + tid]);             \
    LGKM_BARRIER();                                                          \
    _Pragma("unroll")                                                        \
    for (int mi = 0; mi < 4; ++mi)                                           \
      _Pragma("unroll")                                                      \
      for (int r = 0; r < 4; ++r) {                                          \
        const int row = (mi << 4) + (lg << 2) + r;                           \
        const float rinv = rowstat[row];                                     \
        float* orow = out + (size_t)((M0V) + row) * KOUT + (wv << 6) + lr;   \
        _Pragma("unroll")                                                    \
        for (int ni = 0; ni < 4; ++ni)                                       \
          orow[ni << 4] = acc[mi][ni][r] * rinv;                             \
      }                                                                      \
  } while (0)

  // ================= TILE 0 =================
  ZERO_ACC();
  LOADB(bfrA, t0);
  LOADA(av0, xb0, t0);
  LOADA(av1, xb0, (t0 + 1) & 15);
  LOADA(av2, xb0, (t0 + 2) & 15);
  WRITEA(av0, 0);
  LGKM_BARRIER();

  STEP( 0, bfrA, bfrB, av1, av0, xb0);
  STEP( 1, bfrB, bfrA, av2, av1, xb0);
  STEP( 2, bfrA, bfrB, av0, av2, xb0);
  STEP( 3, bfrB, bfrA, av1, av0, xb0);
  STEP( 4, bfrA, bfrB, av2, av1, xb0);
  STEP( 5, bfrB, bfrA, av0, av2, xb0);
  STEP( 6, bfrA, bfrB, av1, av0, xb0);
  STEP( 7, bfrB, bfrA, av2, av1, xb0);
  STEP( 8, bfrA, bfrB, av0, av2, xb0);
  STEP( 9, bfrB, bfrA, av1, av0, xb0);
  STEP(10, bfrA, bfrB, av2, av1, xb0);
  STEP(11, bfrB, bfrA, av0, av2, xb0);
  STEP(12, bfrA, bfrB, av1, av0, xb0);
  // tail with tile-1 prefetch hooks in the dead LOADA slots:
  LOADB(bfrA, (14 + t0) & 15);
  LOADA(av1, xb1, t0);                 // tile-1 A(step0)
  COMPUTE(1, bfrB);                    // s=13
  WRITEA(av2, 0);                      // A(14) -> buf0
  LGKM_BARRIER();
  LOADB(bfrB, (15 + t0) & 15);
  LOADA(av2, xb1, (t0 + 1) & 15);      // tile-1 A(step1)
  COMPUTE(0, bfrA);                    // s=14
  WRITEA(av0, 1);                      // A(15) -> buf1
  LGKM_BARRIER();
  LOADB(bfrA, t0);                     // tile-1 B(step0)
  LOADA(av0, xb1, (t0 + 2) & 15);      // tile-1 A(step2)
  COMPUTE(1, bfrB);                    // s=15
  LGKM_BARRIER();                      // buf reads done; epilogue aliases smem

  EPILOGUE(m0a, (m0a >> 10));
  LGKM_BARRIER();                      // rowstat reads done before tile-1 WRITEA

  // ================= TILE 1 =================
  ZERO_ACC();
  WRITEA(av1, 0);                      // A'(step0) already in regs
  LGKM_BARRIER();

  STEP( 0, bfrA, bfrB, av2, av1, xb1);
  STEP( 1, bfrB, bfrA, av0, av2, xb1);
  STEP( 2, bfrA, bfrB, av1, av0, xb1);
  STEP( 3, bfrB, bfrA, av2, av1, xb1);
  STEP( 4, bfrA, bfrB, av0, av2, xb1);
  STEP( 5, bfrB, bfrA, av1, av0, xb1);
  STEP( 6, bfrA, bfrB, av2, av1, xb1);
  STEP( 7, bfrB, bfrA, av0, av2, xb1);
  STEP( 8, bfrA, bfrB, av1, av0, xb1);
  STEP( 9, bfrB, bfrA, av2, av1, xb1);
  STEP(10, bfrA, bfrB, av0, av2, xb1);
  STEP(11, bfrB, bfrA, av1, av0, xb1);
  STEP(12, bfrA, bfrB, av2, av1, xb1);
  // tail (no further prefetch):
  LOADB(bfrA, (14 + t0) & 15);
  COMPUTE(1, bfrB);                    // s=13
  WRITEA(av0, 0);                      // A'(14) -> buf0
  LGKM_BARRIER();
  LOADB(bfrB, (15 + t0) & 15);
  COMPUTE(0, bfrA);                    // s=14
  WRITEA(av1, 1);                      // A'(15) -> buf1
  LGKM_BARRIER();
  COMPUTE(1, bfrB);                    // s=15
  LGKM_BARRIER();

  EPILOGUE(m0b, (m0b >> 10));

#undef ZERO_ACC
#undef LOADA
#undef LOADB
#undef WRITEA
#undef COMPUTE
#undef STEP
#undef EPILOGUE
}

extern "C" void kernel_launch(void* const* d_in, const int* in_sizes, int n_in,
                              void* d_out, int out_size, void* d_ws, size_t ws_size,
                              hipStream_t stream) {
  (void)in_sizes; (void)n_in; (void)out_size; (void)ws_size;
  const float* x   = (const float*)d_in[0];
  const float* y   = (const float*)d_in[1];
  const float* Wch = (const float*)d_in[2];
  const float* bch = (const float*)d_in[3];
  const float* Wy  = (const float*)d_in[4];
  float* out = (float*)d_out;
  unsigned short* wbf = (unsigned short*)d_ws;                 // 512 KB
  float* biasws = (float*)((char*)d_ws + 512 * 1024);          // 64 KB

  hipLaunchKernelGGL(prep_kernel, dim3(320), dim3(256), 0, stream,
                     Wch, y, Wy, bch, wbf, biasws);
  hipLaunchKernelGGL(fused_kernel, dim3(512), dim3(256), 0, stream,
                     x, wbf, biasws, out);
}

// Round 14
// 118.132 us; speedup vs baseline: 1.1244x; 1.1244x over previous
//
#include <hip/hip_runtime.h>

// Problem: BS=64, N=1024, XC=1024, K=256, YS=768
//   y_k[b,k]   = sum_s y[b,s] * W_y[k,s]
//   z[b,n,k]   = tanh( sum_c x[b,n,c]*W_ch[k,c] + b_ch[k] + y_k[b,k] )
//   out[b*n,k] = softmax_k(z)
// R14: WAVE-OWNS-ROWS decomposition. Wave = 16 rows x 256 cols.
//  A: loaded DIRECTLY global->reg in MFMA fragment order (lane: row l&15,
//     k-window (l>>4)*8), packed to bf16 in-reg. No LDS, no sharing, no
//     barrier ever waits on A. 1x traffic (rows are wave-private).
//  B: block-shared, global_load_lds DMA of pre-formatted bf16 fragments,
//     2x32KB dbuf; 16 barriers total, each gating only an L2-resident DMA
//     issued ~2 steps earlier (vmcnt(4), drained A-loads are >=3 steps old).
//  Softmax: wave-private (rows in one wave) -> epilogue has NO LDS/barriers.

#define XC    1024
#define KOUT  256
#define LDSZ  65536     // 2 x 32KB B tile buffers

typedef float        f32x4_t  __attribute__((ext_vector_type(4)));
typedef unsigned int u32x4_t  __attribute__((ext_vector_type(4)));
typedef unsigned int u32x2_t  __attribute__((ext_vector_type(2)));
typedef __bf16       bf16x8_t __attribute__((ext_vector_type(8)));

__device__ __forceinline__ unsigned short f2bf(float f) {
  unsigned int u = __float_as_uint(f);
  u += 0x7fffu + ((u >> 16) & 1u);        // RNE (prep kernel)
  return (unsigned short)(u >> 16);
}

// biased round-half-away pack (R12/R13-verified: absmax unchanged)
__device__ __forceinline__ unsigned int pack2bf(float a, float b) {
  unsigned int ua = __float_as_uint(a) + 0x8000u;
  unsigned int ub = __float_as_uint(b) + 0x8000u;
  return (ua >> 16) | (ub & 0xffff0000u);
}

__device__ __forceinline__ float fast_tanh(float v) {
  float e = __expf(2.0f * v);
  return 1.0f - 2.0f / (e + 1.0f);
}

__device__ __forceinline__ void async_copy16(void* lds, const void* g) {
  __builtin_amdgcn_global_load_lds(
      (const __attribute__((address_space(1))) void*)g,
      (__attribute__((address_space(3))) void*)lds, 16, 0, 0);
}

#define PIPE_WAIT_(N) asm volatile("s_waitcnt vmcnt(" #N ")" ::: "memory")
#define PIPE_WAIT(N)  PIPE_WAIT_(N)

// ---- prep kernel: unchanged (wbf frag-order cvt + bias GEMV)
__global__ void prep_kernel(const float* __restrict__ Wch,
                            const float* __restrict__ y,
                            const float* __restrict__ Wy,
                            const float* __restrict__ bch,
                            unsigned short* __restrict__ wbf,
                            float* __restrict__ biasws) {
  if (blockIdx.x < 256) {
    const int k = blockIdx.x;
    const int u = threadIdx.x;
    f32x4_t v = ((const f32x4_t*)(Wch + k * XC))[u];
    const int c0   = u << 2;
    const int t    = c0 >> 6;
    const int ch   = (c0 & 63) >> 3;
    const int kk   = ch >> 2;
    const int lg   = ch & 3;
    const int half = (c0 >> 2) & 1;
    const int wv   = k >> 6;
    const int ni   = (k >> 4) & 3;
    const int lr   = k & 15;
    const int lane = (lg << 4) | lr;
    unsigned int lo = (unsigned int)f2bf(v.x) | ((unsigned int)f2bf(v.y) << 16);
    unsigned int hi = (unsigned int)f2bf(v.z) | ((unsigned int)f2bf(v.w) << 16);
    char* p = (char*)wbf +
              ((size_t)((((t << 2) + wv) * 2 + kk) * 4 + ni) << 10) +
              (lane << 4) + (half << 3);
    *(u32x2_t*)p = (u32x2_t){lo, hi};
  } else {
    __shared__ __align__(16) float ys[768];
    const int b = blockIdx.x - 256;
    const int k = threadIdx.x;
    for (int i = k; i < 768; i += 256) ys[i] = y[b * 768 + i];
    __syncthreads();
    const f32x4_t* w4 = (const f32x4_t*)(Wy + k * 768);
    const f32x4_t* y4 = (const f32x4_t*)ys;
    float s = 0.f;
#pragma unroll 8
    for (int i = 0; i < 192; ++i) {
      f32x4_t w = w4[i], a = y4[i];
      s = fmaf(w.x, a.x, s); s = fmaf(w.y, a.y, s);
      s = fmaf(w.z, a.z, s); s = fmaf(w.w, a.w, s);
    }
    biasws[b * 256 + k] = s + bch[k];
  }
}

// ---- main fused kernel: 4 waves x (16 rows x 256 cols) = 64 rows/block.
__global__ __launch_bounds__(256, 2) void fused_kernel(
    const float* __restrict__ x, const unsigned short* __restrict__ wbf,
    const float* __restrict__ bias, float* __restrict__ out) {
  __shared__ __align__(16) unsigned char smem[LDSZ];
  const int tid = threadIdx.x;
  const int l   = tid & 63;
  const int w   = tid >> 6;            // wave 0..3 -> rows [16w, 16w+16)
  const int lr  = l & 15;              // row within wave's 16 (A) / col (B)
  const int lg  = l >> 4;              // k-window (A/B frags)
  const int m0  = blockIdx.x << 6;
  const int bidx = m0 >> 10;
  const int t0  = blockIdx.x & 15;     // K-phase rotation (R9, +6%)

  f32x4_t acc[16];                     // 16 col-groups x f32x4 (lit-indexed)
#pragma unroll
  for (int i = 0; i < 16; ++i) acc[i] = (f32x4_t){0.f, 0.f, 0.f, 0.f};

  // A: lane covers row m0 + w*16 + lr, k-window lg*8 within each K32 half
  const char* xrow = (const char*)x +
      ((size_t)(m0 + (w << 4) + lr) << 12) + (lg << 5);
  const char* wsrc = (const char*)wbf;
  f32x4_t av0[2], av1[2], av2[2], av3[2];   // 4-deep A prefetch, NAMED

  // A load for K32 step s: tile=((s>>1)+t0)&15, half=s&1
#define LOADA(dst, s_) do {                                                  \
    const int off_ = (((((s_) >> 1) + t0) & 15) << 8) + (((s_) & 1) << 7);   \
    dst[0] = *(const f32x4_t*)(xrow + off_);                                 \
    dst[1] = *(const f32x4_t*)(xrow + off_ + 16);                            \
  } while (0)

  // DMA B K64-tile (logical T_, rotated) into buf T_&1: linear 32KB copy
#define DMAB(T_) do {                                                        \
    const int tile_ = ((T_) + t0) & 15;                                      \
    const char* g_ = wsrc + ((size_t)tile_ << 15) + (w << 13) + (l << 4);    \
    unsigned char* d_ = smem + (((T_) & 1) << 15) + (w << 13);               \
    _Pragma("unroll")                                                        \
    for (int i_ = 0; i_ < 8; ++i_)                                           \
      async_copy16(d_ + (i_ << 10), g_ + (i_ << 10));                        \
  } while (0)

#define PACK(avC)                                                            \
    u32x4_t afu_;                                                            \
    afu_[0] = pack2bf(avC[0].x, avC[0].y);                                   \
    afu_[1] = pack2bf(avC[0].z, avC[0].w);                                   \
    afu_[2] = pack2bf(avC[1].x, avC[1].y);                                   \
    afu_[3] = pack2bf(avC[1].z, avC[1].w);                                   \
    bf16x8_t afr_ = __builtin_bit_cast(bf16x8_t, afu_);

#define MFMAS(bufL, kkL) do {                                                \
    const u32x4_t* bB_ = (const u32x4_t*)(smem + ((bufL) << 15));            \
    _Pragma("unroll")                                                        \
    for (int wv2 = 0; wv2 < 4; ++wv2) {                                      \
      bf16x8_t bfr_[4];                                                      \
      _Pragma("unroll")                                                      \
      for (int ni = 0; ni < 4; ++ni)                                         \
        bfr_[ni] = __builtin_bit_cast(bf16x8_t,                              \
            bB_[(((((wv2 << 1) | (kkL)) << 2) | ni) << 6) + l]);             \
      _Pragma("unroll")                                                      \
      for (int ni = 0; ni < 4; ++ni)                                         \
        acc[(wv2 << 2) | ni] = __builtin_amdgcn_mfma_f32_16x16x32_bf16(      \
            afr_, bfr_[ni], acc[(wv2 << 2) | ni], 0, 0, 0);                  \
    }                                                                        \
  } while (0)

#define BARRIER(VM) do {                                                     \
    PIPE_WAIT(VM);                                                           \
    __builtin_amdgcn_s_barrier();                                            \
    __builtin_amdgcn_sched_barrier(0);                                       \
  } while (0)

  // even K32 step s=2T: DMA next tile, pack A, prefetch A(s+4), 16 MFMA
#define STEPE(T_, avC, DODMA, DOLA) {                                        \
    if (DODMA) DMAB((T_) + 1);                                               \
    PACK(avC);                                                               \
    if (DOLA) LOADA(avC, 2 * (T_) + 4);                                      \
    MFMAS((T_) & 1, 0);                                                      \
  }
  // odd step s=2T+1: pack, prefetch A(s+4), 16 MFMA, barrier (counted vm)
#define STEPO(T_, avC, DOLA, DOBAR, VM) {                                    \
    PACK(avC);                                                               \
    if (DOLA) LOADA(avC, 2 * (T_) + 5);                                      \
    MFMAS((T_) & 1, 1);                                                      \
    if (DOBAR) BARRIER(VM);                                                  \
  }

  // prologue: stage B tile 0 (buf0), A(0..3) in flight
  DMAB(0);
  LOADA(av0, 0); LOADA(av1, 1); LOADA(av2, 2); LOADA(av3, 3);
  BARRIER(8);                 // drains the 8 DMA ops; all A stays in flight

  STEPE( 0, av0, 1, 1)  STEPO( 0, av1, 1, 1, 4)
  STEPE( 1, av2, 1, 1)  STEPO( 1, av3, 1, 1, 4)
  STEPE( 2, av0, 1, 1)  STEPO( 2, av1, 1, 1, 4)
  STEPE( 3, av2, 1, 1)  STEPO( 3, av3, 1, 1, 4)
  STEPE( 4, av0, 1, 1)  STEPO( 4, av1, 1, 1, 4)
  STEPE( 5, av2, 1, 1)  STEPO( 5, av3, 1, 1, 4)
  STEPE( 6, av0, 1, 1)  STEPO( 6, av1, 1, 1, 4)
  STEPE( 7, av2, 1, 1)  STEPO( 7, av3, 1, 1, 4)
  STEPE( 8, av0, 1, 1)  STEPO( 8, av1, 1, 1, 4)
  STEPE( 9, av2, 1, 1)  STEPO( 9, av3, 1, 1, 4)
  STEPE(10, av0, 1, 1)  STEPO(10, av1, 1, 1, 4)
  STEPE(11, av2, 1, 1)  STEPO(11, av3, 1, 1, 4)
  STEPE(12, av0, 1, 1)  STEPO(12, av1, 1, 1, 4)
  STEPE(13, av2, 1, 1)  STEPO(13, av3, 1, 1, 4)
  STEPE(14, av0, 1, 0)  STEPO(14, av1, 0, 1, 0)
  STEPE(15, av2, 0, 0)  STEPO(15, av3, 0, 0, 0)

#undef LOADA
#undef DMAB
#undef PACK
#undef MFMAS
#undef BARRIER
#undef STEPE
#undef STEPO

  // ---- epilogue: wave-private tanh + softmax + store. NO LDS, NO barrier.
  // C/D layout: lane holds rows lg*4+r (r=0..3) of the wave's 16, col c*16+lr.
  float brow[16];
#pragma unroll
  for (int c = 0; c < 16; ++c)
    brow[c] = bias[(bidx << 8) + (c << 4) + lr];

#pragma unroll
  for (int c = 0; c < 16; ++c)
#pragma unroll
    for (int r = 0; r < 4; ++r)
      acc[c][r] = fast_tanh(acc[c][r] + brow[c]);

#pragma unroll
  for (int r = 0; r < 4; ++r) {
    float m = acc[0][r];
#pragma unroll
    for (int c = 1; c < 16; ++c) m = fmaxf(m, acc[c][r]);
    m = fmaxf(m, __shfl_xor(m, 1));
    m = fmaxf(m, __shfl_xor(m, 2));
    m = fmaxf(m, __shfl_xor(m, 4));
    m = fmaxf(m, __shfl_xor(m, 8));
    float ssum = 0.f;
#pragma unroll
    for (int c = 0; c < 16; ++c) {
      float e = __expf(acc[c][r] - m);
      acc[c][r] = e;
      ssum += e;
    }
    ssum += __shfl_xor(ssum, 1);
    ssum += __shfl_xor(ssum, 2);
    ssum += __shfl_xor(ssum, 4);
    ssum += __shfl_xor(ssum, 8);
    const float rinv = 1.0f / ssum;
    float* orow = out + ((size_t)(m0 + (w << 4) + (lg << 2) + r) << 8) + lr;
#pragma unroll
    for (int c = 0; c < 16; ++c)
      orow[c << 4] = acc[c][r] * rinv;
  }
}

extern "C" void kernel_launch(void* const* d_in, const int* in_sizes, int n_in,
                              void* d_out, int out_size, void* d_ws, size_t ws_size,
                              hipStream_t stream) {
  (void)in_sizes; (void)n_in; (void)out_size; (void)ws_size;
  const float* x   = (const float*)d_in[0];
  const float* y   = (const float*)d_in[1];
  const float* Wch = (const float*)d_in[2];
  const float* bch = (const float*)d_in[3];
  const float* Wy  = (const float*)d_in[4];
  float* out = (float*)d_out;
  unsigned short* wbf = (unsigned short*)d_ws;                 // 512 KB
  float* biasws = (float*)((char*)d_ws + 512 * 1024);          // 64 KB

  hipLaunchKernelGGL(prep_kernel, dim3(320), dim3(256), 0, stream,
                     Wch, y, Wy, bch, wbf, biasws);
  hipLaunchKernelGGL(fused_kernel, dim3(1024), dim3(256), 0, stream,
                     x, wbf, biasws, out);
}

// Round 15
// 110.989 us; speedup vs baseline: 1.1968x; 1.0644x over previous
//
#include <hip/hip_runtime.h>

// Problem: BS=64, N=1024, XC=1024, K=256, YS=768
//   y_k[b,k]   = sum_s y[b,s] * W_y[k,s]
//   z[b,n,k]   = tanh( sum_c x[b,n,c]*W_ch[k,c] + b_ch[k] + y_k[b,k] )
//   out[b*n,k] = softmax_k(z)
// bf16 MFMA GEMM (f32 acc) fused with tanh+softmax epilogue.
// R15 = R9 (best measured: 111.4us) + pack2bf staging cvt (VALU cut,
//       accuracy-verified in R12/R13/R14: absmax identical 6.1e-5).
// R9 structure: 64 rows/block, 4 waves x 64 cols, BK=64, 16 steps fully
// instantiated with named registers; A 3-deep reg prefetch -> XOR-swizzled
// LDS dbuf; B fragment-ordered global->reg dbuf; lgkm-only barriers;
// per-block K-phase rotation t0 = bid & 15 (HBM channel decorrelation, +6%).

#define XC    1024
#define KOUT  256
#define NT    16        // K-steps: 1024 / 64
#define LDSZ  16384     // A double-buffer: 2 x 8KB (epilogue scratch aliases)

typedef float        f32x4_t  __attribute__((ext_vector_type(4)));
typedef unsigned int u32x4_t  __attribute__((ext_vector_type(4)));
typedef unsigned int u32x2_t  __attribute__((ext_vector_type(2)));
typedef __bf16       bf16x8_t __attribute__((ext_vector_type(8)));

__device__ __forceinline__ unsigned short f2bf(float f) {
  unsigned int u = __float_as_uint(f);
  u += 0x7fffu + ((u >> 16) & 1u);        // RNE (prep kernel only)
  return (unsigned short)(u >> 16);
}

// biased round-half-away pack: 2 floats -> 2 bf16 (0.5-ulp; verified)
__device__ __forceinline__ unsigned int pack2bf(float a, float b) {
  unsigned int ua = __float_as_uint(a) + 0x8000u;
  unsigned int ub = __float_as_uint(b) + 0x8000u;
  return (ua >> 16) | (ub & 0xffff0000u);
}

__device__ __forceinline__ float fast_tanh(float v) {
  float e = __expf(2.0f * v);
  return 1.0f - 2.0f / (e + 1.0f);
}

// lgkm-only barrier: ds_writes visible, global loads STAY IN FLIGHT.
#define LGKM_BARRIER() do {                                  \
    asm volatile("s_waitcnt lgkmcnt(0)" ::: "memory");       \
    __builtin_amdgcn_s_barrier();                            \
    __builtin_amdgcn_sched_barrier(0);                       \
  } while (0)

// ---- prep kernel: blocks 0..255 convert W_ch -> fragment-ordered bf16;
//      blocks 256..319 compute bias[b][k] = y[b]·W_y[k] + b_ch[k] (f32).
__global__ void prep_kernel(const float* __restrict__ Wch,
                            const float* __restrict__ y,
                            const float* __restrict__ Wy,
                            const float* __restrict__ bch,
                            unsigned short* __restrict__ wbf,
                            float* __restrict__ biasws) {
  if (blockIdx.x < 256) {
    const int k = blockIdx.x;            // 0..255
    const int u = threadIdx.x;           // 0..255 ; c0 = 4u
    f32x4_t v = ((const f32x4_t*)(Wch + k * XC))[u];
    const int c0   = u << 2;
    const int t    = c0 >> 6;            // K-step tile
    const int ch   = (c0 & 63) >> 3;     // 16B chunk within tile
    const int kk   = ch >> 2;
    const int lg   = ch & 3;
    const int half = (c0 >> 2) & 1;      // which 8B of the 16B chunk
    const int wv   = k >> 6;
    const int ni   = (k >> 4) & 3;
    const int lr   = k & 15;
    const int lane = (lg << 4) | lr;
    unsigned int lo = (unsigned int)f2bf(v.x) | ((unsigned int)f2bf(v.y) << 16);
    unsigned int hi = (unsigned int)f2bf(v.z) | ((unsigned int)f2bf(v.w) << 16);
    char* p = (char*)wbf +
              ((size_t)((((t << 2) + wv) * 2 + kk) * 4 + ni) << 10) +
              (lane << 4) + (half << 3);
    *(u32x2_t*)p = (u32x2_t){lo, hi};
  } else {
    __shared__ __align__(16) float ys[768];
    const int b = blockIdx.x - 256;      // 0..63
    const int k = threadIdx.x;           // 0..255
    for (int i = k; i < 768; i += 256) ys[i] = y[b * 768 + i];
    __syncthreads();
    const f32x4_t* w4 = (const f32x4_t*)(Wy + k * 768);
    const f32x4_t* y4 = (const f32x4_t*)ys;
    float s = 0.f;
#pragma unroll 8
    for (int i = 0; i < 192; ++i) {
      f32x4_t w = w4[i], a = y4[i];
      s = fmaf(w.x, a.x, s); s = fmaf(w.y, a.y, s);
      s = fmaf(w.z, a.z, s); s = fmaf(w.w, a.w, s);
    }
    biasws[b * 256 + k] = s + bch[k];
  }
}

// ---- main fused kernel: 64 rows/block x full 256 cols; BK=64.
__global__ __launch_bounds__(256, 2) void fused_kernel(
    const float* __restrict__ x, const unsigned short* __restrict__ wbf,
    const float* __restrict__ bias, float* __restrict__ out) {
  __shared__ __align__(16) unsigned char smem[LDSZ];
  const int tid = threadIdx.x;
  const int l   = tid & 63;
  const int wv  = tid >> 6;            // wave 0..3 -> output cols [64w,64w+64)
  const int lr  = l & 15;
  const int lg  = l >> 4;
  const int m0  = blockIdx.x << 6;     // first of 64 rows
  const int bidx = m0 >> 10;           // batch index
  const int rr  = tid >> 4;            // A-stage: row-within-16-group
  const int c4  = tid & 15;            // A-stage: float4 column chunk
  const int t0  = blockIdx.x & 15;     // per-block K-phase rotation

  f32x4_t acc[4][4];
#pragma unroll
  for (int i = 0; i < 4; ++i)
#pragma unroll
    for (int j = 0; j < 4; ++j) acc[i][j] = (f32x4_t){0.f, 0.f, 0.f, 0.f};

  const float* xb = x + (size_t)m0 * XC + (size_t)rr * XC + (c4 << 2);
  const char* wsrc = (const char*)wbf + (wv << 13) + (l << 4);
  f32x4_t av0[4], av1[4], av2[4];      // 3-deep A prefetch, NAMED slots
  bf16x8_t bfrA[8], bfrB[8];           // [kk*4+nj], double-buffered

#define LOADA(dst, tt) do {                                                  \
    _Pragma("unroll")                                                        \
    for (int j = 0; j < 4; ++j)                                              \
      dst[j] = *(const f32x4_t*)(xb + (size_t)(j << 4) * XC + ((tt) << 6));  \
  } while (0)

#define LOADB(dst, tt) do {                                                  \
    const char* g = wsrc + (size_t)(tt) * 32768;                             \
    _Pragma("unroll")                                                        \
    for (int f = 0; f < 8; ++f)                                              \
      dst[f] = __builtin_bit_cast(bf16x8_t, *(const u32x4_t*)(g + (f << 10)));\
  } while (0)

#define WRITEA(src, buf) do {                                                \
    _Pragma("unroll")                                                        \
    for (int j = 0; j < 4; ++j) {                                            \
      const int row = (j << 4) + rr;                                         \
      unsigned int lo = pack2bf(src[j].x, src[j].y);                         \
      unsigned int hi = pack2bf(src[j].z, src[j].w);                         \
      char* p = (char*)smem + ((buf) << 13) + row * 128 +                    \
                (((c4 >> 1) ^ (row & 7)) << 4) + ((c4 & 1) << 3);            \
      *(u32x2_t*)p = (u32x2_t){lo, hi};                                      \
    }                                                                        \
  } while (0)

#define COMPUTE(buf, bsrc) do {                                              \
    const u32x4_t* aB = (const u32x4_t*)(smem + ((buf) << 13));              \
    _Pragma("unroll")                                                        \
    for (int kk = 0; kk < 2; ++kk) {                                         \
      const int cs = ((kk << 2) | lg) ^ (lr & 7);                            \
      bf16x8_t afr[4];                                                       \
      _Pragma("unroll")                                                      \
      for (int mi = 0; mi < 4; ++mi)                                         \
        afr[mi] = __builtin_bit_cast(bf16x8_t, aB[(((mi << 4) + lr) << 3) + cs]);\
      _Pragma("unroll")                                                      \
      for (int mi = 0; mi < 4; ++mi)                                         \
        _Pragma("unroll")                                                    \
        for (int nj = 0; nj < 4; ++nj)                                       \
          acc[mi][nj] = __builtin_amdgcn_mfma_f32_16x16x32_bf16(             \
              afr[mi], bsrc[(kk << 2) | nj], acc[mi][nj], 0, 0, 0);          \
    }                                                                        \
  } while (0)

  // STEP(s): literal control flow; K-tile index rotated by t0 at runtime.
#define STEP(s, bC, bN, aW, aL) do {                                         \
    if ((s) + 1 < NT) LOADB(bN, (((s) + 1 + t0) & 15));                      \
    if ((s) + 3 < NT) LOADA(aL, (((s) + 3 + t0) & 15));                      \
    COMPUTE((s) & 1, bC);                                                    \
    if ((s) + 1 < NT) { WRITEA(aW, ((s) + 1) & 1); LGKM_BARRIER(); }         \
  } while (0)

  // prologue: B(t0), A(t0..t0+2) in flight; stage A(t0) into buf0.
  LOADB(bfrA, t0);
  LOADA(av0, t0);
  LOADA(av1, (t0 + 1) & 15);
  LOADA(av2, (t0 + 2) & 15);
  WRITEA(av0, 0);          // drains B+A(t0); later prefetches stay in flight
  LGKM_BARRIER();

  STEP( 0, bfrA, bfrB, av1, av0);
  STEP( 1, bfrB, bfrA, av2, av1);
  STEP( 2, bfrA, bfrB, av0, av2);
  STEP( 3, bfrB, bfrA, av1, av0);
  STEP( 4, bfrA, bfrB, av2, av1);
  STEP( 5, bfrB, bfrA, av0, av2);
  STEP( 6, bfrA, bfrB, av1, av0);
  STEP( 7, bfrB, bfrA, av2, av1);
  STEP( 8, bfrA, bfrB, av0, av2);
  STEP( 9, bfrB, bfrA, av1, av0);
  STEP(10, bfrA, bfrB, av2, av1);
  STEP(11, bfrB, bfrA, av0, av2);
  STEP(12, bfrA, bfrB, av1, av0);
  STEP(13, bfrB, bfrA, av2, av1);
  STEP(14, bfrA, bfrB, av0, av2);
  STEP(15, bfrB, bfrA, av1, av0);

  __syncthreads();             // full drain before scratch aliases A buffer

#undef LOADA
#undef LOADB
#undef WRITEA
#undef COMPUTE
#undef STEP

  // ---- epilogue: tanh, row-softmax over 256 cols, store
  float* wred    = (float*)smem;           // [4 waves][64 rows]
  float* rowstat = (float*)(smem + 1024);  // [64 rows]

  float brow[4];
#pragma unroll
  for (int ni = 0; ni < 4; ++ni)
    brow[ni] = bias[(bidx << 8) + (wv << 6) + (ni << 4) + lr];

#pragma unroll
  for (int mi = 0; mi < 4; ++mi)
#pragma unroll
    for (int ni = 0; ni < 4; ++ni)
#pragma unroll
      for (int r = 0; r < 4; ++r)
        acc[mi][ni][r] = fast_tanh(acc[mi][ni][r] + brow[ni]);

  // per-row max: 4 local cols, then butterfly over the 16-lane col group
#pragma unroll
  for (int mi = 0; mi < 4; ++mi)
#pragma unroll
    for (int r = 0; r < 4; ++r) {
      float m = fmaxf(fmaxf(acc[mi][0][r], acc[mi][1][r]),
                      fmaxf(acc[mi][2][r], acc[mi][3][r]));
      m = fmaxf(m, __shfl_xor(m, 1));
      m = fmaxf(m, __shfl_xor(m, 2));
      m = fmaxf(m, __shfl_xor(m, 4));
      m = fmaxf(m, __shfl_xor(m, 8));
      if (lr == 0) wred[(wv << 6) + (mi << 4) + (lg << 2) + r] = m;
    }
  __syncthreads();
  if (tid < 64)
    rowstat[tid] = fmaxf(fmaxf(wred[tid], wred[64 + tid]),
                         fmaxf(wred[128 + tid], wred[192 + tid]));
  __syncthreads();

  // exp + per-row sum
#pragma unroll
  for (int mi = 0; mi < 4; ++mi)
#pragma unroll
    for (int r = 0; r < 4; ++r) {
      const int row = (mi << 4) + (lg << 2) + r;
      const float m = rowstat[row];
      float s = 0.f;
#pragma unroll
      for (int ni = 0; ni < 4; ++ni) {
        float e = __expf(acc[mi][ni][r] - m);
        acc[mi][ni][r] = e;
        s += e;
      }
      s += __shfl_xor(s, 1);
      s += __shfl_xor(s, 2);
      s += __shfl_xor(s, 4);
      s += __shfl_xor(s, 8);
      if (lr == 0) wred[(wv << 6) + row] = s;
    }
  __syncthreads();
  if (tid < 64)
    rowstat[tid] = 1.0f / (wred[tid] + wred[64 + tid] +
                           wred[128 + tid] + wred[192 + tid]);
  __syncthreads();

  // normalize + store (16 lanes = 64B dense segments)
#pragma unroll
  for (int mi = 0; mi < 4; ++mi)
#pragma unroll
    for (int r = 0; r < 4; ++r) {
      const int row = (mi << 4) + (lg << 2) + r;
      const float rinv = rowstat[row];
      float* orow = out + (size_t)(m0 + row) * KOUT + (wv << 6) + lr;
#pragma unroll
      for (int ni = 0; ni < 4; ++ni)
        orow[ni << 4] = acc[mi][ni][r] * rinv;
    }
}

extern "C" void kernel_launch(void* const* d_in, const int* in_sizes, int n_in,
                              void* d_out, int out_size, void* d_ws, size_t ws_size,
                              hipStream_t stream) {
  (void)in_sizes; (void)n_in; (void)out_size; (void)ws_size;
  const float* x   = (const float*)d_in[0];
  const float* y   = (const float*)d_in[1];
  const float* Wch = (const float*)d_in[2];
  const float* bch = (const float*)d_in[3];
  const float* Wy  = (const float*)d_in[4];
  float* out = (float*)d_out;
  unsigned short* wbf = (unsigned short*)d_ws;                 // 512 KB
  float* biasws = (float*)((char*)d_ws + 512 * 1024);          // 64 KB

  hipLaunchKernelGGL(prep_kernel, dim3(320), dim3(256), 0, stream,
                     Wch, y, Wy, bch, wbf, biasws);
  hipLaunchKernelGGL(fused_kernel, dim3(1024), dim3(256), 0, stream,
                     x, wbf, biasws, out);
}